// Round 6
// baseline (369.918 us; speedup 1.0000x reference)
//
#include <hip/hip_runtime.h>
#include <math.h>

// CapsuleLayer dynamic routing, fused recompute formulation.
// x[B=128, J=2048, I=8], W[J, K=32, I, D=16] -> v[B, K, D]
// b_t = (sum_{tau<t} v_tau) . u_hat, so keep only vsum[b,k,d] and recompute
// u_hat each sweep.
//
// R5 -> R6: LDS read bytes are the wall (each wave reads the full 16 KB W
// slice per j; 256 KB/CU/j ~ 33 us/sweep + 14 us conflicts from an aliased
// swizzle). Fix: W converted ONCE to bf16 by a prep kernel and stored
// PRE-SWIZZLED in d_ws (16 MB). Sweeps stage 8 KB/j verbatim via
// global_load_lds and read one ds_read_b128 per (i) = 8 bf16 d-values,
// unpacked with shl/and. Swizzle L ^ (((L>>8)&7)<<4) -> balanced 8 slots
// x 8 lanes per instruction = conflict-free. Precision: W-only bf16,
// s RMS err ~5e-4 << 1.4e-2 threshold.

constexpr int Bn = 128;
constexpr int Jn = 2048;
constexpr int In = 8;
constexpr int Kn = 32;
constexpr int Dn = 16;
constexpr int KD = Kn * Dn;          // 512
constexpr int CELLS = Bn * KD;       // 65536

constexpr int JT    = 32;            // j per workgroup
constexpr int NJB   = Jn / JT;       // 64 j-blocks
constexpr int WAVES = 4;
constexpr int BLOCK = WAVES * 64;    // 256 threads
constexpr int BW    = 2;             // batches per wave
constexpr int BGW   = WAVES * BW;    // 8 batches per workgroup
constexpr int NBB   = Bn / BGW;      // 16 b-blocks
constexpr int GRID_SWEEP = NBB * NJB; // 1024 workgroups = 4/CU
constexpr int SLICE_F32 = Kn * In * Dn * 4;  // 16384 B per j (fp32)
constexpr int SLICE_B16 = Kn * In * Dn * 2;  // 8192 B per j (bf16)

__device__ __forceinline__ unsigned bf16rne(float f) {
    const unsigned u = __float_as_uint(f);
    return (u + 0x7FFFu + ((u >> 16) & 1u)) >> 16;   // round-nearest-even
}

// One-time: W fp32 -> bf16, stored PRE-SWIZZLED so sweeps can global_load_lds
// verbatim and read conflict-free. Logical byte L in an 8 KB slice:
// L = k*256 + i*32 + dh*16 + (d&7)*2 ; stored at L ^ (((L>>8)&7)<<4)
// (XOR touches bits 4-6 only; its key bits 8-10 are invariant -> involution.)
__global__ __launch_bounds__(256)
void prep_wbf16(const float* __restrict__ W, unsigned int* __restrict__ Wb)
{
    const int g  = blockIdx.x * 256 + threadIdx.x;   // u32 index
    const int j  = g >> 11;                          // 2048 u32 per slice
    const int L  = (g & 2047) << 2;                  // logical byte in slice
    const int k  = L >> 8;
    const int i5 = (L >> 5) & 7;
    const int dh = (L >> 4) & 1;
    const int dm = (L & 15) >> 1;                    // 0,2,4,6
    const float2 f = *reinterpret_cast<const float2*>(
        W + (size_t)j * 4096 + k * 128 + i5 * 16 + dh * 8 + dm);
    const unsigned lo = bf16rne(f.x), hi = bf16rne(f.y);
    const int A = L ^ (((L >> 8) & 7) << 4);
    Wb[((size_t)j * SLICE_B16 + A) >> 2] = lo | (hi << 16);
}

// PHASE: 0 = uniform c (softmax of zeros), 1/2 = softmax(vsum . u_hat)
// ATOMIC: atomicAdd fallback for tiny workspace. WB16: bf16 W path.
template <int PHASE, bool ATOMIC, bool WB16>
__global__ __launch_bounds__(BLOCK, 4)
void sweep_kernel(const float* __restrict__ x, const float* __restrict__ W,
                  const unsigned short* __restrict__ Wb,
                  const float* __restrict__ vsum, float* __restrict__ sout)
{
    constexpr int SLICE = WB16 ? SLICE_B16 : SLICE_F32;
    __shared__ __align__(16) char wlds[2 * SLICE];

    const int jb    = blockIdx.x % NJB;
    const int b0    = (blockIdx.x / NJB) * BGW;
    const int tid   = threadIdx.x;
    const int wave  = tid >> 6;
    const int lane  = tid & 63;
    const int kk    = lane >> 1;             // output capsule
    const int dh    = lane & 1;              // d-half (8 floats)
    const int bbase = b0 + wave * BW;
    const int kswz  = (kk & 7) << 4;         // read-side swizzle key
    const int LbB16 = kk * 256 + dh * 16;    // bf16 slice base (bit4==0)
    const int LbF32 = kk * 512 + dh * 32;    // fp32 slice base

    // stage W[j] slice into LDS buf (async, linear dest)
    auto stage = [&](int jidx, int buf) {
        if (WB16) {
            const char* src = (const char*)Wb + (size_t)jidx * SLICE_B16;
#pragma unroll
            for (int c = 0; c < 2; ++c) {
                const int M = c * 4096 + tid * 16;
                __builtin_amdgcn_global_load_lds(
                    (const __attribute__((address_space(1))) void*)(src + M),
                    (__attribute__((address_space(3))) void*)(wlds + buf * SLICE + M),
                    16, 0, 0);
            }
        } else {
            const char* src = (const char*)W + (size_t)jidx * SLICE_F32;
#pragma unroll
            for (int c = 0; c < 4; ++c) {
                const int M = c * 4096 + tid * 16;
                const int G = M ^ (((M >> 9) & 7) << 4);   // source swizzle
                __builtin_amdgcn_global_load_lds(
                    (const __attribute__((address_space(1))) void*)(src + G),
                    (__attribute__((address_space(3))) void*)(wlds + buf * SLICE + M),
                    16, 0, 0);
            }
        }
    };

    // vsum[b, kk, dh*8..+8] is j-invariant: hoist to registers.
    float vs[BW][8];
    if (PHASE != 0) {
#pragma unroll
        for (int bb = 0; bb < BW; ++bb) {
            const float* vp = vsum + ((size_t)(bbase + bb) * Kn + kk) * Dn + dh * 8;
            const float4 a  = *reinterpret_cast<const float4*>(vp);
            const float4 b4 = *reinterpret_cast<const float4*>(vp + 4);
            vs[bb][0] = a.x;  vs[bb][1] = a.y;  vs[bb][2] = a.z;  vs[bb][3] = a.w;
            vs[bb][4] = b4.x; vs[bb][5] = b4.y; vs[bb][6] = b4.z; vs[bb][7] = b4.w;
        }
    }

    float sacc[BW][8];
#pragma unroll
    for (int bb = 0; bb < BW; ++bb)
#pragma unroll
        for (int r = 0; r < 8; ++r) sacc[bb][r] = 0.f;

    const int j0 = jb * JT;
    stage(j0, 0);        // prologue
    __syncthreads();     // drains vmcnt

#pragma unroll 2
    for (int jj = 0; jj < JT; ++jj) {
        const int j   = j0 + jj;
        const int buf = jj & 1;

        if (jj + 1 < JT)   // prefetch next slice; lands under this j's compute
            stage(j + 1, buf ^ 1);

        // x[b, j, 0..7]: wave-uniform broadcast loads
        float xv[BW][8];
#pragma unroll
        for (int bb = 0; bb < BW; ++bb) {
            const float* xp = x + ((size_t)(bbase + bb) * Jn + j) * In;
            const float4 xa = *reinterpret_cast<const float4*>(xp);
            const float4 xb = *reinterpret_cast<const float4*>(xp + 4);
            xv[bb][0] = xa.x; xv[bb][1] = xa.y; xv[bb][2] = xa.z; xv[bb][3] = xa.w;
            xv[bb][4] = xb.x; xv[bb][5] = xb.y; xv[bb][6] = xb.z; xv[bb][7] = xb.w;
        }

        // u_hat[b, kk, j, dh*8+r] = sum_i x[b,j,i] * W[j,kk,i,dh*8+r]
        float uh[BW][8];
#pragma unroll
        for (int bb = 0; bb < BW; ++bb)
#pragma unroll
            for (int r = 0; r < 8; ++r) uh[bb][r] = 0.f;

        const char* wb = wlds + buf * SLICE;
#pragma unroll
        for (int i = 0; i < In; ++i) {
            float w8[8];
            if (WB16) {
                const uint4 wv = *reinterpret_cast<const uint4*>(
                    wb + ((LbB16 + i * 32) ^ kswz));
                w8[0] = __uint_as_float(wv.x << 16);
                w8[1] = __uint_as_float(wv.x & 0xFFFF0000u);
                w8[2] = __uint_as_float(wv.y << 16);
                w8[3] = __uint_as_float(wv.y & 0xFFFF0000u);
                w8[4] = __uint_as_float(wv.z << 16);
                w8[5] = __uint_as_float(wv.z & 0xFFFF0000u);
                w8[6] = __uint_as_float(wv.w << 16);
                w8[7] = __uint_as_float(wv.w & 0xFFFF0000u);
            } else {
                const int a0 = (LbF32 + i * 64) ^ kswz;
                const float4 wa = *reinterpret_cast<const float4*>(wb + a0);
                const float4 wc = *reinterpret_cast<const float4*>(wb + (a0 ^ 16));
                w8[0] = wa.x; w8[1] = wa.y; w8[2] = wa.z; w8[3] = wa.w;
                w8[4] = wc.x; w8[5] = wc.y; w8[6] = wc.z; w8[7] = wc.w;
            }
#pragma unroll
            for (int bb = 0; bb < BW; ++bb)
#pragma unroll
                for (int r = 0; r < 8; ++r)
                    uh[bb][r] = fmaf(xv[bb][i], w8[r], uh[bb][r]);
        }

        if (PHASE == 0) {
#pragma unroll
            for (int bb = 0; bb < BW; ++bb)
#pragma unroll
                for (int r = 0; r < 8; ++r) sacc[bb][r] += uh[bb][r];
        } else {
#pragma unroll
            for (int bb = 0; bb < BW; ++bb) {
                float p = vs[bb][0] * uh[bb][0];
#pragma unroll
                for (int r = 1; r < 8; ++r) p = fmaf(vs[bb][r], uh[bb][r], p);
                p += __shfl_xor(p, 1);   // combine d-halves -> full dot

                // no max-subtraction: |p| <= ~12 << 88, exp can't overflow
                const float e = __expf(p);
                float ss = e;
#pragma unroll
                for (int mk = 2; mk <= 32; mk <<= 1)
                    ss += __shfl_xor(ss, mk);
#if __has_builtin(__builtin_amdgcn_rcpf)
                const float c = e * __builtin_amdgcn_rcpf(ss);
#else
                const float c = e / ss;
#endif
#pragma unroll
                for (int r = 0; r < 8; ++r)
                    sacc[bb][r] = fmaf(c, uh[bb][r], sacc[bb][r]);
            }
        }
        __syncthreads();   // buf reads done + next-buf stage landed
    }

    // epilogue: dump per-wave s partials
#pragma unroll
    for (int bb = 0; bb < BW; ++bb) {
        const int b = bbase + bb;
        const size_t cell = ((size_t)b * Kn + kk) * Dn + dh * 8;
        if (ATOMIC) {
#pragma unroll
            for (int r = 0; r < 8; ++r)
                atomicAdd(sout + cell + r, sacc[bb][r]);
        } else {
            const float4 f0 = make_float4(sacc[bb][0], sacc[bb][1], sacc[bb][2], sacc[bb][3]);
            const float4 f1 = make_float4(sacc[bb][4], sacc[bb][5], sacc[bb][6], sacc[bb][7]);
            float* dst = sout + (size_t)jb * CELLS + cell;
            *reinterpret_cast<float4*>(dst)     = f0;
            *reinterpret_cast<float4*>(dst + 4) = f1;
        }
    }
}

// Reduce partials, squash, update vsum; final phase writes v to d_out.
template <int PHASE, bool ATOMIC>
__global__ __launch_bounds__(256)
void squash_kernel(float* __restrict__ sbuf, float* __restrict__ vsum,
                   float* __restrict__ outv)
{
    const int t = blockIdx.x * blockDim.x + threadIdx.x;   // 0..16383
    const size_t c4 = (size_t)t * 4;

    float4 s;
    if (ATOMIC) {
        s = *reinterpret_cast<const float4*>(sbuf + c4);
        *reinterpret_cast<float4*>(sbuf + c4) = make_float4(0.f, 0.f, 0.f, 0.f);
    } else {
        s = make_float4(0.f, 0.f, 0.f, 0.f);
#pragma unroll 4
        for (int p = 0; p < NJB; ++p) {
            const float4 v = *reinterpret_cast<const float4*>(sbuf + (size_t)p * CELLS + c4);
            s.x += v.x; s.y += v.y; s.z += v.z; s.w += v.w;
        }
    }

    if (PHASE == 0) {  // uniform c = 1/K folded out of the sweep
        const float sc = 1.f / 32.f;
        s.x *= sc; s.y *= sc; s.z *= sc; s.w *= sc;
    }

    float s2 = s.x * s.x + s.y * s.y + s.z * s.z + s.w * s.w;
    s2 += __shfl_xor(s2, 1);
    s2 += __shfl_xor(s2, 2);
    const float scale = s2 / ((1.f + s2) * sqrtf(s2 + 1e-7f));
    const float4 v4 = make_float4(s.x * scale, s.y * scale, s.z * scale, s.w * scale);

    if (PHASE == 2) {
        *reinterpret_cast<float4*>(outv + c4) = v4;
    } else if (PHASE == 0) {
        *reinterpret_cast<float4*>(vsum + c4) = v4;
    } else {
        float4 o = *reinterpret_cast<const float4*>(vsum + c4);
        o.x += v4.x; o.y += v4.y; o.z += v4.z; o.w += v4.w;
        *reinterpret_cast<float4*>(vsum + c4) = o;
    }
}

extern "C" void kernel_launch(void* const* d_in, const int* in_sizes, int n_in,
                              void* d_out, int out_size, void* d_ws, size_t ws_size,
                              hipStream_t stream)
{
    const float* x = (const float*)d_in[0];
    const float* W = (const float*)d_in[1];
    float* out = (float*)d_out;

    const size_t partial_bytes = (size_t)NJB * CELLS * sizeof(float);       // 16 MB
    const size_t vsum_bytes    = (size_t)CELLS * sizeof(float);             // 256 KB
    const size_t wb_bytes      = (size_t)Jn * SLICE_B16;                    // 16 MB

    const dim3 gs(GRID_SWEEP), bs(BLOCK);
    const dim3 gq(CELLS / 4 / 256), bq(256);
    const dim3 gp((Jn * (SLICE_B16 / 4)) / 256), bp(256);                   // 16384 blocks

    if (ws_size >= partial_bytes + vsum_bytes + wb_bytes) {
        float* partial = (float*)d_ws;
        float* vsum    = (float*)((char*)d_ws + partial_bytes);
        unsigned int*  wbw = (unsigned int*)((char*)d_ws + partial_bytes + vsum_bytes);
        const unsigned short* wb = (const unsigned short*)wbw;
        prep_wbf16<<<gp, bp, 0, stream>>>(W, wbw);
        sweep_kernel<0, false, true><<<gs, bs, 0, stream>>>(x, W, wb, vsum, partial);
        squash_kernel<0, false><<<gq, bq, 0, stream>>>(partial, vsum, out);
        sweep_kernel<1, false, true><<<gs, bs, 0, stream>>>(x, W, wb, vsum, partial);
        squash_kernel<1, false><<<gq, bq, 0, stream>>>(partial, vsum, out);
        sweep_kernel<2, false, true><<<gs, bs, 0, stream>>>(x, W, wb, vsum, partial);
        squash_kernel<2, false><<<gq, bq, 0, stream>>>(partial, vsum, out);
    } else if (ws_size >= partial_bytes + vsum_bytes) {
        // fp32-LDS path (R5 behavior)
        float* partial = (float*)d_ws;
        float* vsum    = (float*)((char*)d_ws + partial_bytes);
        sweep_kernel<0, false, false><<<gs, bs, 0, stream>>>(x, W, nullptr, vsum, partial);
        squash_kernel<0, false><<<gq, bq, 0, stream>>>(partial, vsum, out);
        sweep_kernel<1, false, false><<<gs, bs, 0, stream>>>(x, W, nullptr, vsum, partial);
        squash_kernel<1, false><<<gq, bq, 0, stream>>>(partial, vsum, out);
        sweep_kernel<2, false, false><<<gs, bs, 0, stream>>>(x, W, nullptr, vsum, partial);
        squash_kernel<2, false><<<gq, bq, 0, stream>>>(partial, vsum, out);
    } else {
        // tiny-workspace fallback: single accumulator + atomics
        float* sbuf = (float*)d_ws;
        float* vsum = (float*)((char*)d_ws + vsum_bytes);
        hipMemsetAsync(sbuf, 0, vsum_bytes, stream);
        sweep_kernel<0, true, false><<<gs, bs, 0, stream>>>(x, W, nullptr, vsum, sbuf);
        squash_kernel<0, true><<<gq, bq, 0, stream>>>(sbuf, vsum, out);
        sweep_kernel<1, true, false><<<gs, bs, 0, stream>>>(x, W, nullptr, vsum, sbuf);
        squash_kernel<1, true><<<gq, bq, 0, stream>>>(sbuf, vsum, out);
        sweep_kernel<2, true, false><<<gs, bs, 0, stream>>>(x, W, nullptr, vsum, sbuf);
        squash_kernel<2, true><<<gq, bq, 0, stream>>>(sbuf, vsum, out);
    }
}